// Round 2
// baseline (92.112 us; speedup 1.0000x reference)
//
#include <hip/hip_runtime.h>
#include <hip/hip_bf16.h>

#define VOCAB 128
#define HIDDEN 128

typedef float f32x4 __attribute__((ext_vector_type(4)));

// Precompute T1[v][o] = sum_h emb[v][h] * W[o][h]        + b[o]
//            T2[v][o] = sum_h emb[v][h] * W[o][128 + h]
__global__ void precompute_tables(const float* __restrict__ emb,
                                  const float* __restrict__ W,
                                  const float* __restrict__ b,
                                  float* __restrict__ T1,
                                  float* __restrict__ T2) {
    int v = blockIdx.x;
    int o = threadIdx.x;
    const float* er = emb + v * HIDDEN;        // broadcast across block
    const float* wr = W + o * (2 * HIDDEN);    // per-thread row
    float s1 = 0.f, s2 = 0.f;
#pragma unroll 8
    for (int h = 0; h < HIDDEN; ++h) {
        float ev = er[h];
        s1 += ev * wr[h];
        s2 += ev * wr[HIDDEN + h];
    }
    T1[v * HIDDEN + o] = s1 + b[o];
    T2[v * HIDDEN + o] = s2;
}

// 16 lanes per edge; each lane produces 8 floats (2 x float4, 32 B).
// out[e*128 + q*8 ..] = T1[z[src[e]]][q*8..] + T2[z[dst[e]]][q*8..]
__global__ __launch_bounds__(256) void edge_gather_add(
        const int* __restrict__ z,
        const int* __restrict__ src,
        const int* __restrict__ dst,
        const float* __restrict__ T1,
        const float* __restrict__ T2,
        float* __restrict__ out,
        int E) {
    int total = E * 16;
    int stride = gridDim.x * blockDim.x;
    for (int idx = blockIdx.x * blockDim.x + threadIdx.x; idx < total; idx += stride) {
        int e = idx >> 4;
        int q = idx & 15;
        int zs = z[src[e]];
        int zd = z[dst[e]];
        const f32x4* a = reinterpret_cast<const f32x4*>(T1 + zs * HIDDEN + q * 8);
        const f32x4* c = reinterpret_cast<const f32x4*>(T2 + zd * HIDDEN + q * 8);
        f32x4 r0 = a[0] + c[0];
        f32x4 r1 = a[1] + c[1];
        f32x4* o = reinterpret_cast<f32x4*>(out + (size_t)e * HIDDEN + q * 8);
        __builtin_nontemporal_store(r0, o);
        __builtin_nontemporal_store(r1, o + 1);
    }
}

extern "C" void kernel_launch(void* const* d_in, const int* in_sizes, int n_in,
                              void* d_out, int out_size, void* d_ws, size_t ws_size,
                              hipStream_t stream) {
    const int*   z    = (const int*)d_in[0];          // [N_NODES]
    const int*   ei   = (const int*)d_in[1];          // [2, E] row-major
    const float* emb  = (const float*)d_in[2];        // [128, 128]
    const float* W    = (const float*)d_in[3];        // [128, 256]
    const float* b    = (const float*)d_in[4];        // [128]
    float*       out  = (float*)d_out;                // [E, 128]

    int E = in_sizes[1] / 2;
    const int* src = ei;
    const int* dst = ei + E;

    float* T1 = (float*)d_ws;                         // 128*128 f32 = 64 KB
    float* T2 = T1 + VOCAB * HIDDEN;                  // 64 KB

    precompute_tables<<<VOCAB, HIDDEN, 0, stream>>>(emb, W, b, T1, T2);

    int block = 256;
    int grid = 2048;  // 32 waves/CU, grid-stride over E*16 units
    edge_gather_add<<<grid, block, 0, stream>>>(z, src, dst, T1, T2, out, E);
}

// Round 3
// 53.393 us; speedup vs baseline: 1.7252x; 1.7252x over previous
//
#include <hip/hip_runtime.h>
#include <hip/hip_bf16.h>

#define VOCAB 128
#define HIDDEN 128

typedef float f32x4 __attribute__((ext_vector_type(4)));

// Precompute T1[v][o] = sum_h emb[v][h] * W[o][h]        + b[o]
//            T2[v][o] = sum_h emb[v][h] * W[o][128 + h]
__global__ void precompute_tables(const float* __restrict__ emb,
                                  const float* __restrict__ W,
                                  const float* __restrict__ b,
                                  float* __restrict__ T1,
                                  float* __restrict__ T2) {
    int v = blockIdx.x;
    int o = threadIdx.x;
    const float* er = emb + v * HIDDEN;        // broadcast across block
    const float* wr = W + o * (2 * HIDDEN);    // per-thread row
    float s1 = 0.f, s2 = 0.f;
#pragma unroll 8
    for (int h = 0; h < HIDDEN; ++h) {
        float ev = er[h];
        s1 += ev * wr[h];
        s2 += ev * wr[HIDDEN + h];
    }
    T1[v * HIDDEN + o] = s1 + b[o];
    T2[v * HIDDEN + o] = s2;
}

// 32 lanes per edge, one float4 per lane: each wave store instruction is
// 64 lanes x 16 B = 1024 B fully contiguous (whole cachelines) -> nt-safe.
__global__ __launch_bounds__(256) void edge_gather_add(
        const int* __restrict__ z,
        const int* __restrict__ src,
        const int* __restrict__ dst,
        const float* __restrict__ T1,
        const float* __restrict__ T2,
        float* __restrict__ out,
        int E) {
    int total = E * 32;
    int stride = gridDim.x * blockDim.x;
    for (int idx = blockIdx.x * blockDim.x + threadIdx.x; idx < total; idx += stride) {
        int e = idx >> 5;
        int q = idx & 31;
        int zs = z[src[e]];
        int zd = z[dst[e]];
        f32x4 a = *reinterpret_cast<const f32x4*>(T1 + zs * HIDDEN + q * 4);
        f32x4 c = *reinterpret_cast<const f32x4*>(T2 + zd * HIDDEN + q * 4);
        f32x4 r = a + c;
        __builtin_nontemporal_store(r, reinterpret_cast<f32x4*>(out + (size_t)e * HIDDEN + q * 4));
    }
}

extern "C" void kernel_launch(void* const* d_in, const int* in_sizes, int n_in,
                              void* d_out, int out_size, void* d_ws, size_t ws_size,
                              hipStream_t stream) {
    const int*   z    = (const int*)d_in[0];          // [N_NODES]
    const int*   ei   = (const int*)d_in[1];          // [2, E] row-major
    const float* emb  = (const float*)d_in[2];        // [128, 128]
    const float* W    = (const float*)d_in[3];        // [128, 256]
    const float* b    = (const float*)d_in[4];        // [128]
    float*       out  = (float*)d_out;                // [E, 128]

    int E = in_sizes[1] / 2;
    const int* src = ei;
    const int* dst = ei + E;

    float* T1 = (float*)d_ws;                         // 128*128 f32 = 64 KB
    float* T2 = T1 + VOCAB * HIDDEN;                  // 64 KB

    precompute_tables<<<VOCAB, HIDDEN, 0, stream>>>(emb, W, b, T1, T2);

    int block = 256;
    int grid = 2048;  // grid-stride over E*32 units
    edge_gather_add<<<grid, block, 0, stream>>>(z, src, dst, T1, T2, out, E);
}

// Round 4
// 53.192 us; speedup vs baseline: 1.7317x; 1.0038x over previous
//
#include <hip/hip_runtime.h>
#include <hip/hip_bf16.h>

#define VOCAB 128
#define HIDDEN 128

typedef float f32x4 __attribute__((ext_vector_type(4)));

// Block b computes column o=b of both tables:
//   T1[v][o] = sum_h emb[v][h] * W[o][h]       + b[o]
//   T2[v][o] = sum_h emb[v][h] * W[o][128+h]
// emb is staged in LDS (coalesced), lane = v. W row o / b[o] are
// wave-uniform -> scalar loads. LDS row stride 129 -> bank (v+h)%32,
// 2-way across 64 lanes = conflict-free.
__global__ __launch_bounds__(128) void precompute_tables(
        const float* __restrict__ emb,
        const float* __restrict__ W,
        const float* __restrict__ b,
        float* __restrict__ T1,
        float* __restrict__ T2) {
    __shared__ float es[VOCAB * (HIDDEN + 1)];
    int t = threadIdx.x;
    int o = blockIdx.x;

    // Stage emb: 16384 floats, coalesced float4 loads.
    for (int i = 0; i < (VOCAB * HIDDEN) / (128 * 4); ++i) {
        int f = (i * 128 + t) * 4;           // float index, multiple of 4
        f32x4 val = *reinterpret_cast<const f32x4*>(emb + f);
        int v = f >> 7;                       // f / 128
        int h = f & 127;
        float* d = es + v * (HIDDEN + 1) + h; // rows of 128 stay intact (128%4==0)
        d[0] = val.x; d[1] = val.y; d[2] = val.z; d[3] = val.w;
    }
    __syncthreads();

    int v = t;                                // one lane per vocab row
    const float* wr = W + o * (2 * HIDDEN);   // uniform -> scalar loads
    const float* er = es + v * (HIDDEN + 1);
    float s1 = 0.f, s2 = 0.f;
#pragma unroll 16
    for (int h = 0; h < HIDDEN; ++h) {
        float ev = er[h];
        s1 += ev * wr[h];
        s2 += ev * wr[HIDDEN + h];
    }
    T1[v * HIDDEN + o] = s1 + b[o];
    T2[v * HIDDEN + o] = s2;
}

// 32 lanes per edge, one float4 per lane: each wave store instruction is
// 64 lanes x 16 B = 1024 B fully contiguous (whole cachelines) -> nt-safe.
__global__ __launch_bounds__(256) void edge_gather_add(
        const int* __restrict__ z,
        const int* __restrict__ src,
        const int* __restrict__ dst,
        const float* __restrict__ T1,
        const float* __restrict__ T2,
        float* __restrict__ out,
        int E) {
    int total = E * 32;
    int stride = gridDim.x * blockDim.x;
    for (int idx = blockIdx.x * blockDim.x + threadIdx.x; idx < total; idx += stride) {
        int e = idx >> 5;
        int q = idx & 31;
        int zs = z[src[e]];
        int zd = z[dst[e]];
        f32x4 a = *reinterpret_cast<const f32x4*>(T1 + zs * HIDDEN + q * 4);
        f32x4 c = *reinterpret_cast<const f32x4*>(T2 + zd * HIDDEN + q * 4);
        f32x4 r = a + c;
        __builtin_nontemporal_store(r, reinterpret_cast<f32x4*>(out + (size_t)e * HIDDEN + q * 4));
    }
}

extern "C" void kernel_launch(void* const* d_in, const int* in_sizes, int n_in,
                              void* d_out, int out_size, void* d_ws, size_t ws_size,
                              hipStream_t stream) {
    const int*   z    = (const int*)d_in[0];          // [N_NODES]
    const int*   ei   = (const int*)d_in[1];          // [2, E] row-major
    const float* emb  = (const float*)d_in[2];        // [128, 128]
    const float* W    = (const float*)d_in[3];        // [128, 256]
    const float* b    = (const float*)d_in[4];        // [128]
    float*       out  = (float*)d_out;                // [E, 128]

    int E = in_sizes[1] / 2;
    const int* src = ei;
    const int* dst = ei + E;

    float* T1 = (float*)d_ws;                         // 128*128 f32 = 64 KB
    float* T2 = T1 + VOCAB * HIDDEN;                  // 64 KB

    precompute_tables<<<VOCAB, 128, 0, stream>>>(emb, W, b, T1, T2);

    int block = 256;
    int grid = 2048;  // grid-stride over E*32 units
    edge_gather_add<<<grid, block, 0, stream>>>(z, src, dst, T1, T2, out, E);
}